// Round 1
// baseline (214.105 us; speedup 1.0000x reference)
//
#include <hip/hip_runtime.h>

// ---------- helpers ----------
typedef __bf16 bf16x8 __attribute__((ext_vector_type(8)));
typedef float  f32x4  __attribute__((ext_vector_type(4)));

static __device__ __forceinline__ unsigned short f32_to_bf16(float f){
  unsigned u = __float_as_uint(f);
  u += 0x7fffu + ((u >> 16) & 1u);          // round-to-nearest-even
  return (unsigned short)(u >> 16);
}
static __device__ __forceinline__ float bf16_to_f32(unsigned short h){
  return __uint_as_float(((unsigned)h) << 16);
}

#define GLOAD_LDS16(g, l)                                                        \
  __builtin_amdgcn_global_load_lds((const __attribute__((address_space(1))) void*)(g), \
                                   (__attribute__((address_space(3))) void*)(l), 16, 0, 0)

// ---------- K0: weight conversion + BN folding ----------
__global__ __launch_bounds__(256) void prep_kernel(
    const float* __restrict__ w1, const float* __restrict__ w2,
    const float* __restrict__ b1, const float* __restrict__ g1, const float* __restrict__ be1,
    const float* __restrict__ m1, const float* __restrict__ v1,
    const float* __restrict__ b2, const float* __restrict__ g2, const float* __restrict__ be2,
    const float* __restrict__ m2, const float* __restrict__ v2,
    unsigned short* __restrict__ w1b, unsigned short* __restrict__ w2b,
    float* __restrict__ sc1, float* __restrict__ sh1,
    float* __restrict__ sc2, float* __restrict__ sh2)
{
  int i = blockIdx.x * 256 + threadIdx.x;
  int stride = gridDim.x * 256;
  for (int k = i; k < 512 * 2048; k += stride) w1b[k] = f32_to_bf16(w1[k]);
  for (int k = i; k < 256 * 512;  k += stride) w2b[k] = f32_to_bf16(w2[k]);
  if (i < 512){
    float s = g1[i] * rsqrtf(v1[i] + 1e-5f);
    sc1[i] = s;
    sh1[i] = (b1[i] - m1[i]) * s + be1[i];   // bias folded into BN shift
  } else if (i - 512 < 256){
    int o = i - 512;
    float s = g2[o] * rsqrtf(v2[o] + 1e-5f);
    sc2[o] = s;
    sh2[o] = (b2[o] - m2[o]) * s + be2[o];
  }
}

// ---------- K1: ROI align -> x_bf16 [128*49][2048] ----------
// grid: 128 rois * 32 channel-chunks (64 ch each); block 256 = (64 bin-lanes, 4 csub)
__global__ __launch_bounds__(256) void roi_align_kernel(
    const float* __restrict__ feat, const float* __restrict__ boxes,
    unsigned short* __restrict__ xb)
{
  int roi = blockIdx.x >> 5;
  int c0  = (blockIdx.x & 31) << 6;
  __shared__ int   sIdx[16][49];
  __shared__ float sW[16][49];
  __shared__ float xt[49][65];             // +1 pad: conflict-free column writes
  int t = threadIdx.x;

  int   b   = (int)boxes[roi * 5 + 0];
  float bx1 = boxes[roi * 5 + 1], by1 = boxes[roi * 5 + 2];
  float bx2 = boxes[roi * 5 + 3], by2 = boxes[roi * 5 + 4];
  float rw = fmaxf(bx2 - bx1, 1.f), rh = fmaxf(by2 - by1, 1.f);
  float bw = rw * (1.f / 7.f), bh = rh * (1.f / 7.f);

  if (t < 196){                            // 49 bins * 4 sample points
    int bin = t >> 2, s = t & 3;
    int ky = bin / 7, kx = bin - ky * 7;
    int sy = s >> 1, sx = s & 1;
    float yy = by1 + ((float)ky + ((float)sy + 0.5f) * 0.5f) * bh;
    float xx = bx1 + ((float)kx + ((float)sx + 0.5f) * 0.5f) * bw;
    bool vy = (yy >= -1.f) && (yy <= 64.f);
    bool vx = (xx >= -1.f) && (xx <= 64.f);
    float yc = fminf(fmaxf(yy, 0.f), 63.f);
    float xc = fminf(fmaxf(xx, 0.f), 63.f);
    int iy0 = (int)yc, ix0 = (int)xc;      // floor (nonneg)
    int iy1 = min(iy0 + 1, 63), ix1 = min(ix0 + 1, 63);
    float fy = yc - (float)iy0, fx = xc - (float)ix0;
    float v = (vy && vx) ? 0.25f : 0.f;    // /4 = mean over SR*SR folded in
    float wy0 = 1.f - fy, wx0 = 1.f - fx;
    sIdx[s * 4 + 0][bin] = iy0 * 64 + ix0;  sW[s * 4 + 0][bin] = wy0 * wx0 * v;
    sIdx[s * 4 + 1][bin] = iy0 * 64 + ix1;  sW[s * 4 + 1][bin] = wy0 * fx  * v;
    sIdx[s * 4 + 2][bin] = iy1 * 64 + ix0;  sW[s * 4 + 2][bin] = fy  * wx0 * v;
    sIdx[s * 4 + 3][bin] = iy1 * 64 + ix1;  sW[s * 4 + 3][bin] = fy  * fx  * v;
  }
  __syncthreads();

  int bin = t & 63, csub = t >> 6;
  if (bin < 49){
    int idx[16]; float wg[16];
    #pragma unroll
    for (int i = 0; i < 16; ++i){ idx[i] = sIdx[i][bin]; wg[i] = sW[i][bin]; }
    const float* Fb = feat + ((size_t)b * 2048 + (size_t)c0) * 4096;
    for (int j = 0; j < 16; ++j){
      int cl = (j << 2) | csub;
      const float* p = Fb + (size_t)cl * 4096;
      float acc = 0.f;
      #pragma unroll
      for (int i = 0; i < 16; ++i) acc += wg[i] * p[idx[i]];
      xt[bin][cl] = acc;
    }
  }
  __syncthreads();

  size_t base = ((size_t)roi * 49) * 2048 + (size_t)c0;
  for (int r = (t >> 6); r < 49; r += 4)
    xb[base + (size_t)r * 2048 + (t & 63)] = f32_to_bf16(xt[r][t & 63]);
}

// ---------- K2/K3: bf16 GEMM, B-transposed input, fused scale/shift + ReLU ----------
// C[m][n] = relu( (sum_k A[m][k]*Bt[n][k]) * scale[n] + shift[n] ), bf16 out
template<int BM, int BN>
__global__ __launch_bounds__(256) void gemm_bt_relu(
    const unsigned short* __restrict__ A, const unsigned short* __restrict__ Bt,
    const float* __restrict__ scale, const float* __restrict__ shift,
    unsigned short* __restrict__ C, int M, int N, int K)
{
  constexpr int BK = 64;
  constexpr int FM = BM / 32;              // wave covers BM/2 rows -> FM 16-frags
  constexpr int FN = BN / 32;
  __shared__ unsigned short lds_a[BM * BK];
  __shared__ unsigned short lds_b[BN * BK];
  int t = threadIdx.x;
  int l = t & 63, wid = t >> 6;
  int wr = wid >> 1, wc = wid & 1;
  int m0 = blockIdx.y * BM, n0 = blockIdx.x * BN;

  f32x4 acc[FM][FN];
  f32x4 z = {0.f, 0.f, 0.f, 0.f};
  #pragma unroll
  for (int m = 0; m < FM; ++m)
    #pragma unroll
    for (int n = 0; n < FN; ++n) acc[m][n] = z;

  const unsigned short* Ab = A  + (size_t)m0 * K;
  const unsigned short* Bb = Bt + (size_t)n0 * K;

  for (int kt = 0; kt < K; kt += BK){
    #pragma unroll
    for (int r = 0; r < BM / 32; ++r){
      int row = r * 32 + (t >> 3);
      GLOAD_LDS16(Ab + (size_t)row * K + kt + (t & 7) * 8,
                  lds_a + row * BK + (t & 7) * 8);
    }
    #pragma unroll
    for (int r = 0; r < BN / 32; ++r){
      int row = r * 32 + (t >> 3);
      GLOAD_LDS16(Bb + (size_t)row * K + kt + (t & 7) * 8,
                  lds_b + row * BK + (t & 7) * 8);
    }
    __syncthreads();
    #pragma unroll
    for (int ks = 0; ks < 2; ++ks){
      bf16x8 af[FM], bfr[FN];
      #pragma unroll
      for (int m = 0; m < FM; ++m)
        af[m] = *reinterpret_cast<const bf16x8*>(
            lds_a + (wr * (BM / 2) + m * 16 + (l & 15)) * BK + ks * 32 + (l >> 4) * 8);
      #pragma unroll
      for (int n = 0; n < FN; ++n)
        bfr[n] = *reinterpret_cast<const bf16x8*>(
            lds_b + (wc * (BN / 2) + n * 16 + (l & 15)) * BK + ks * 32 + (l >> 4) * 8);
      #pragma unroll
      for (int m = 0; m < FM; ++m)
        #pragma unroll
        for (int n = 0; n < FN; ++n)
          acc[m][n] = __builtin_amdgcn_mfma_f32_16x16x32_bf16(af[m], bfr[n], acc[m][n], 0, 0, 0);
    }
    __syncthreads();
  }

  #pragma unroll
  for (int m = 0; m < FM; ++m){
    int gr = m0 + wr * (BM / 2) + m * 16 + (l >> 4) * 4;
    #pragma unroll
    for (int n = 0; n < FN; ++n){
      int gc = n0 + wc * (BN / 2) + n * 16 + (l & 15);
      float sc = scale[gc], sh = shift[gc];
      #pragma unroll
      for (int r = 0; r < 4; ++r){
        float v = acc[m][n][r] * sc + sh;
        v = fmaxf(v, 0.f);
        C[(size_t)(gr + r) * N + gc] = f32_to_bf16(v);
      }
    }
  }
}

// ---------- K4: mean over 49 bins -> out f32 [128][256] ----------
__global__ __launch_bounds__(256) void reduce_kernel(
    const unsigned short* __restrict__ h2, float* __restrict__ out)
{
  int n = blockIdx.x, o = threadIdx.x;
  const unsigned short* p = h2 + (size_t)n * 49 * 256 + o;
  float s = 0.f;
  for (int j = 0; j < 49; ++j) s += bf16_to_f32(p[j * 256]);
  out[n * 256 + o] = s * (1.f / 49.f);
}

// ---------- launch ----------
extern "C" void kernel_launch(void* const* d_in, const int* in_sizes, int n_in,
                              void* d_out, int out_size, void* d_ws, size_t ws_size,
                              hipStream_t stream)
{
  const float* feat  = (const float*)d_in[0];
  const float* boxes = (const float*)d_in[1];
  const float* w1  = (const float*)d_in[2];
  const float* b1  = (const float*)d_in[3];
  const float* g1  = (const float*)d_in[4];
  const float* be1 = (const float*)d_in[5];
  const float* m1  = (const float*)d_in[6];
  const float* v1  = (const float*)d_in[7];
  const float* w2  = (const float*)d_in[8];
  const float* b2  = (const float*)d_in[9];
  const float* g2  = (const float*)d_in[10];
  const float* be2 = (const float*)d_in[11];
  const float* m2  = (const float*)d_in[12];
  const float* v2  = (const float*)d_in[13];
  float* out = (float*)d_out;

  char* ws = (char*)d_ws;
  unsigned short* w1b = (unsigned short*)(ws);                         // 2 MB
  unsigned short* w2b = (unsigned short*)(ws + (2u << 20));            // 256 KB
  float* sc1 = (float*)(ws + (2u << 20) + (256u << 10));
  float* sh1 = sc1 + 512;
  float* sc2 = sh1 + 512;
  float* sh2 = sc2 + 256;
  unsigned short* xb = (unsigned short*)(ws + (4u  << 20));            // 25.7 MB
  unsigned short* h1 = (unsigned short*)(ws + (32u << 20));            // 6.4 MB
  unsigned short* h2 = (unsigned short*)(ws + (40u << 20));            // 3.2 MB
  // total workspace use: 44 MB

  hipLaunchKernelGGL(prep_kernel, dim3(256), dim3(256), 0, stream,
                     w1, w2, b1, g1, be1, m1, v1, b2, g2, be2, m2, v2,
                     w1b, w2b, sc1, sh1, sc2, sh2);
  hipLaunchKernelGGL(roi_align_kernel, dim3(128 * 32), dim3(256), 0, stream,
                     feat, boxes, xb);
  hipLaunchKernelGGL(HIP_KERNEL_NAME(gemm_bt_relu<128, 64>),
                     dim3(512 / 64, 6272 / 128), dim3(256), 0, stream,
                     xb, w1b, sc1, sh1, h1, 6272, 512, 2048);
  hipLaunchKernelGGL(HIP_KERNEL_NAME(gemm_bt_relu<128, 64>),
                     dim3(256 / 64, 6272 / 128), dim3(256), 0, stream,
                     h1, w2b, sc2, sh2, h2, 6272, 256, 512);
  hipLaunchKernelGGL(reduce_kernel, dim3(128), dim3(256), 0, stream, h2, out);
}

// Round 2
// 104.657 us; speedup vs baseline: 2.0458x; 2.0458x over previous
//
#include <hip/hip_runtime.h>

// ---------- helpers ----------
typedef __bf16 bf16x8 __attribute__((ext_vector_type(8)));
typedef float  f32x4  __attribute__((ext_vector_type(4)));
typedef unsigned short u16x8 __attribute__((ext_vector_type(8)));
typedef unsigned int u32;

static __device__ __forceinline__ unsigned short f32_to_bf16(float f){
  unsigned u = __float_as_uint(f);
  u += 0x7fffu + ((u >> 16) & 1u);          // round-to-nearest-even
  return (unsigned short)(u >> 16);
}
static __device__ __forceinline__ float bf16_to_f32(unsigned short h){
  return __uint_as_float(((unsigned)h) << 16);
}

#define GLOAD_LDS16(g, l)                                                        \
  __builtin_amdgcn_global_load_lds((const __attribute__((address_space(1))) void*)(g), \
                                   (__attribute__((address_space(3))) void*)(l), 16, 0, 0)

// ---------- K0: weight conversion + BN folding ----------
__global__ __launch_bounds__(256) void prep_kernel(
    const float* __restrict__ w1, const float* __restrict__ w2,
    const float* __restrict__ b1, const float* __restrict__ g1, const float* __restrict__ be1,
    const float* __restrict__ m1, const float* __restrict__ v1,
    const float* __restrict__ b2, const float* __restrict__ g2, const float* __restrict__ be2,
    const float* __restrict__ m2, const float* __restrict__ v2,
    unsigned short* __restrict__ w1b, unsigned short* __restrict__ w2b,
    float* __restrict__ sc1, float* __restrict__ sh1,
    float* __restrict__ sc2, float* __restrict__ sh2)
{
  int i = blockIdx.x * 256 + threadIdx.x;
  int stride = gridDim.x * 256;
  for (int k = i; k < 512 * 2048; k += stride) w1b[k] = f32_to_bf16(w1[k]);
  for (int k = i; k < 256 * 512;  k += stride) w2b[k] = f32_to_bf16(w2[k]);
  if (i < 512){
    float s = g1[i] * rsqrtf(v1[i] + 1e-5f);
    sc1[i] = s;
    sh1[i] = (b1[i] - m1[i]) * s + be1[i];   // conv bias folded into BN shift
  } else if (i - 512 < 256){
    int o = i - 512;
    float s = g2[o] * rsqrtf(v2[o] + 1e-5f);
    sc2[o] = s;
    sh2[o] = (b2[o] - m2[o]) * s + be2[o];
  }
}

// ---------- K1: conv1 over full map: Zt[b][p][512] = (W1 . F)^T, bf16 ----------
// grid 256 = 4 batches * 64 p-blocks (64 cols each); block 512 thr = 8 waves.
// Each block computes ALL 512 output channels for its 64 spatial positions,
// so F (f32) is streamed from HBM exactly once, converted to bf16 in staging.
__global__ __launch_bounds__(512, 2) void conv1_kernel(
    const unsigned short* __restrict__ w1b,   // [512][2048] bf16, k-contig
    const float* __restrict__ feat,           // [4][2048][4096] f32
    unsigned short* __restrict__ zt)          // [4*4096][512] bf16
{
  __shared__ unsigned short lds_a[512 * 64];  // 64KB, swizzled [o][c]
  __shared__ unsigned short lds_b[64 * 64];   // 8KB, swizzled [p][c]
  int t = threadIdx.x;
  int l = t & 63, wid = t >> 6;
  int bb = blockIdx.x >> 6;
  int p0 = (blockIdx.x & 63) << 6;

  f32x4 acc[4][4];
  f32x4 z4 = {0.f, 0.f, 0.f, 0.f};
  #pragma unroll
  for (int m = 0; m < 4; ++m)
    #pragma unroll
    for (int n = 0; n < 4; ++n) acc[m][n] = z4;

  // A-stage: pre-swizzled global sources so LDS dest stays linear.
  // stored byte L in tile = o*128 + x ; content = element c = ((x ^ ((o&7)<<4))>>1)
  const unsigned short* asrc[8];
  unsigned short* adst[8];
  #pragma unroll
  for (int i = 0; i < 8; ++i){
    int slot = i * 512 + t;
    int o = slot >> 3;
    int x = (slot & 7) << 4;
    int cl = (x ^ ((o & 7) << 4)) >> 1;
    asrc[i] = w1b + (size_t)o * 2048 + cl;
    adst[i] = lds_a + slot * 8;
  }
  // B-stage mapping: thread covers (c0,c0+1) x (p4..p4+3)
  int bp4 = (t & 15) << 2;
  int bcp = t >> 4;              // c-pair index 0..31
  int bc0 = bcp << 1;
  const float* fb0 = feat + ((size_t)(bb * 2048 + bc0)) * 4096 + p0 + bp4;

  for (int kt = 0; kt < 2048; kt += 64){
    // B f32 loads first (oldest in vmcnt queue)
    f32x4 r0 = *(const f32x4*)(fb0 + (size_t)kt * 4096);
    f32x4 r1 = *(const f32x4*)(fb0 + (size_t)kt * 4096 + 4096);
    // A: async global->LDS, 64KB
    #pragma unroll
    for (int i = 0; i < 8; ++i) GLOAD_LDS16(asrc[i] + kt, adst[i]);
    // B: cvt + swizzled ds_write_b32
    #pragma unroll
    for (int i = 0; i < 4; ++i){
      u32 v = ((u32)f32_to_bf16(r0[i])) | (((u32)f32_to_bf16(r1[i])) << 16);
      int p = bp4 + i;
      int cb = (bc0 << 1) ^ ((p & 7) << 4);
      *(u32*)((char*)lds_b + p * 128 + cb) = v;
    }
    __syncthreads();
    #pragma unroll
    for (int ks = 0; ks < 2; ++ks){
      bf16x8 af[4], bfr[4];
      #pragma unroll
      for (int m = 0; m < 4; ++m){
        int o = wid * 64 + m * 16 + (l & 15);
        int cb = ((ks * 32 + (l >> 4) * 8) << 1) ^ ((o & 7) << 4);
        af[m] = *(const bf16x8*)((char*)lds_a + o * 128 + cb);
      }
      #pragma unroll
      for (int n = 0; n < 4; ++n){
        int p = n * 16 + (l & 15);
        int cb = ((ks * 32 + (l >> 4) * 8) << 1) ^ ((p & 7) << 4);
        bfr[n] = *(const bf16x8*)((char*)lds_b + p * 128 + cb);
      }
      #pragma unroll
      for (int m = 0; m < 4; ++m)
        #pragma unroll
        for (int n = 0; n < 4; ++n)
          acc[m][n] = __builtin_amdgcn_mfma_f32_16x16x32_bf16(af[m], bfr[n], acc[m][n], 0, 0, 0);
    }
    __syncthreads();
  }

  // epilogue: transpose 512x64 -> Zt rows via lds_a reuse.
  // LDS layout: byte = p*1024 + (o*2 ^ ((p&7)<<4))
  #pragma unroll
  for (int m = 0; m < 4; ++m){
    int o0 = wid * 64 + m * 16 + (l >> 4) * 4;
    #pragma unroll
    for (int n = 0; n < 4; ++n){
      int p = n * 16 + (l & 15);
      u32 lo = ((u32)f32_to_bf16(acc[m][n][0])) | (((u32)f32_to_bf16(acc[m][n][1])) << 16);
      u32 hi = ((u32)f32_to_bf16(acc[m][n][2])) | (((u32)f32_to_bf16(acc[m][n][3])) << 16);
      unsigned long long v = ((unsigned long long)hi << 32) | lo;
      *(unsigned long long*)((char*)lds_a + p * 1024 + ((o0 * 2) ^ ((p & 7) << 4))) = v;
    }
  }
  __syncthreads();
  {
    int p = t >> 3, a = t & 7;
    size_t rowb = ((size_t)(bb * 4096 + p0 + p)) * 1024;   // bytes
    int swz = (p & 7) << 4;
    #pragma unroll
    for (int j = 0; j < 8; ++j){
      int y = (j * 128 + a * 16) ^ swz;
      f32x4 v = *(const f32x4*)((char*)lds_a + p * 1024 + y);
      *(f32x4*)((char*)zt + rowb + j * 128 + a * 16) = v;
    }
  }
}

// ---------- K2: ROI gather on Zt (512 ch) + BN1 + ReLU -> h1 bf16 [6272][512] ----------
// grid (7 ky, 128 roi); block 256 = 4 waves; wave handles bins kx = w, w+4
__global__ __launch_bounds__(256) void roi_gather_kernel(
    const unsigned short* __restrict__ zt, const float* __restrict__ boxes,
    const float* __restrict__ sc1, const float* __restrict__ sh1,
    unsigned short* __restrict__ h1)
{
  int ky = blockIdx.x, roi = blockIdx.y;
  __shared__ int   sIdx[16][8];
  __shared__ float sW[16][8];
  int t = threadIdx.x;

  int   b   = (int)boxes[roi * 5 + 0];
  float bx1 = boxes[roi * 5 + 1], by1 = boxes[roi * 5 + 2];
  float bx2 = boxes[roi * 5 + 3], by2 = boxes[roi * 5 + 4];
  float rw = fmaxf(bx2 - bx1, 1.f), rh = fmaxf(by2 - by1, 1.f);
  float bw = rw * (1.f / 7.f), bh = rh * (1.f / 7.f);

  if (t < 28){                              // 7 bins * 4 sample points
    int kx = t >> 2, s = t & 3;
    int sy = s >> 1, sx = s & 1;
    float yy = by1 + ((float)ky + ((float)sy + 0.5f) * 0.5f) * bh;
    float xx = bx1 + ((float)kx + ((float)sx + 0.5f) * 0.5f) * bw;
    bool vy = (yy >= -1.f) && (yy <= 64.f);
    bool vx = (xx >= -1.f) && (xx <= 64.f);
    float yc = fminf(fmaxf(yy, 0.f), 63.f);
    float xc = fminf(fmaxf(xx, 0.f), 63.f);
    int iy0 = (int)yc, ix0 = (int)xc;
    int iy1 = min(iy0 + 1, 63), ix1 = min(ix0 + 1, 63);
    float fy = yc - (float)iy0, fx = xc - (float)ix0;
    float v = (vy && vx) ? 0.25f : 0.f;
    float wy0 = 1.f - fy, wx0 = 1.f - fx;
    sIdx[s * 4 + 0][kx] = iy0 * 64 + ix0;  sW[s * 4 + 0][kx] = wy0 * wx0 * v;
    sIdx[s * 4 + 1][kx] = iy0 * 64 + ix1;  sW[s * 4 + 1][kx] = wy0 * fx  * v;
    sIdx[s * 4 + 2][kx] = iy1 * 64 + ix0;  sW[s * 4 + 2][kx] = fy  * wx0 * v;
    sIdx[s * 4 + 3][kx] = iy1 * 64 + ix1;  sW[s * 4 + 3][kx] = fy  * fx  * v;
  }
  __syncthreads();

  int w = t >> 6, l = t & 63;
  f32x4 s0 = *(const f32x4*)(sc1 + l * 8);
  f32x4 s1 = *(const f32x4*)(sc1 + l * 8 + 4);
  f32x4 h0 = *(const f32x4*)(sh1 + l * 8);
  f32x4 hh = *(const f32x4*)(sh1 + l * 8 + 4);
  const unsigned short* zb = zt + ((size_t)b * 4096) * 512 + l * 8;

  for (int kx = w; kx < 7; kx += 4){
    float a[8];
    #pragma unroll
    for (int j = 0; j < 8; ++j) a[j] = 0.f;
    #pragma unroll
    for (int i = 0; i < 16; ++i){
      int idx = sIdx[i][kx];
      float wt = sW[i][kx];
      u16x8 v = *(const u16x8*)(zb + (size_t)idx * 512);
      #pragma unroll
      for (int j = 0; j < 8; ++j) a[j] += wt * bf16_to_f32(v[j]);
    }
    u16x8 o;
    #pragma unroll
    for (int j = 0; j < 4; ++j){
      float v0 = fmaxf(a[j] * s0[j] + h0[j], 0.f);
      float v1 = fmaxf(a[j + 4] * s1[j] + hh[j], 0.f);
      o[j] = f32_to_bf16(v0);
      o[j + 4] = f32_to_bf16(v1);
    }
    *(u16x8*)(h1 + ((size_t)(roi * 49 + ky * 7 + kx)) * 512 + l * 8) = o;
  }
}

// ---------- K3: bf16 GEMM, B-transposed input, fused scale/shift + ReLU ----------
template<int BM, int BN>
__global__ __launch_bounds__(256) void gemm_bt_relu(
    const unsigned short* __restrict__ A, const unsigned short* __restrict__ Bt,
    const float* __restrict__ scale, const float* __restrict__ shift,
    unsigned short* __restrict__ C, int M, int N, int K)
{
  constexpr int BK = 64;
  constexpr int FM = BM / 32;
  constexpr int FN = BN / 32;
  __shared__ unsigned short lds_a[BM * BK];
  __shared__ unsigned short lds_b[BN * BK];
  int t = threadIdx.x;
  int l = t & 63, wid = t >> 6;
  int wr = wid >> 1, wc = wid & 1;
  int m0 = blockIdx.y * BM, n0 = blockIdx.x * BN;

  f32x4 acc[FM][FN];
  f32x4 z = {0.f, 0.f, 0.f, 0.f};
  #pragma unroll
  for (int m = 0; m < FM; ++m)
    #pragma unroll
    for (int n = 0; n < FN; ++n) acc[m][n] = z;

  const unsigned short* Ab = A  + (size_t)m0 * K;
  const unsigned short* Bb = Bt + (size_t)n0 * K;

  for (int kt = 0; kt < K; kt += BK){
    #pragma unroll
    for (int r = 0; r < BM / 32; ++r){
      int row = r * 32 + (t >> 3);
      GLOAD_LDS16(Ab + (size_t)row * K + kt + (t & 7) * 8,
                  lds_a + row * BK + (t & 7) * 8);
    }
    #pragma unroll
    for (int r = 0; r < BN / 32; ++r){
      int row = r * 32 + (t >> 3);
      GLOAD_LDS16(Bb + (size_t)row * K + kt + (t & 7) * 8,
                  lds_b + row * BK + (t & 7) * 8);
    }
    __syncthreads();
    #pragma unroll
    for (int ks = 0; ks < 2; ++ks){
      bf16x8 af[FM], bfr[FN];
      #pragma unroll
      for (int m = 0; m < FM; ++m)
        af[m] = *reinterpret_cast<const bf16x8*>(
            lds_a + (wr * (BM / 2) + m * 16 + (l & 15)) * BK + ks * 32 + (l >> 4) * 8);
      #pragma unroll
      for (int n = 0; n < FN; ++n)
        bfr[n] = *reinterpret_cast<const bf16x8*>(
            lds_b + (wc * (BN / 2) + n * 16 + (l & 15)) * BK + ks * 32 + (l >> 4) * 8);
      #pragma unroll
      for (int m = 0; m < FM; ++m)
        #pragma unroll
        for (int n = 0; n < FN; ++n)
          acc[m][n] = __builtin_amdgcn_mfma_f32_16x16x32_bf16(af[m], bfr[n], acc[m][n], 0, 0, 0);
    }
    __syncthreads();
  }

  #pragma unroll
  for (int m = 0; m < FM; ++m){
    int gr = m0 + wr * (BM / 2) + m * 16 + (l >> 4) * 4;
    #pragma unroll
    for (int n = 0; n < FN; ++n){
      int gc = n0 + wc * (BN / 2) + n * 16 + (l & 15);
      float sc = scale[gc], sh = shift[gc];
      #pragma unroll
      for (int r = 0; r < 4; ++r){
        float v = acc[m][n][r] * sc + sh;
        v = fmaxf(v, 0.f);
        C[(size_t)(gr + r) * N + gc] = f32_to_bf16(v);
      }
    }
  }
}

// ---------- K4: mean over 49 bins -> out f32 [128][256] ----------
__global__ __launch_bounds__(256) void reduce_kernel(
    const unsigned short* __restrict__ h2, float* __restrict__ out)
{
  int n = blockIdx.x, o = threadIdx.x;
  const unsigned short* p = h2 + (size_t)n * 49 * 256 + o;
  float s = 0.f;
  for (int j = 0; j < 49; ++j) s += bf16_to_f32(p[j * 256]);
  out[n * 256 + o] = s * (1.f / 49.f);
}

// ---------- launch ----------
extern "C" void kernel_launch(void* const* d_in, const int* in_sizes, int n_in,
                              void* d_out, int out_size, void* d_ws, size_t ws_size,
                              hipStream_t stream)
{
  const float* feat  = (const float*)d_in[0];
  const float* boxes = (const float*)d_in[1];
  const float* w1  = (const float*)d_in[2];
  const float* b1  = (const float*)d_in[3];
  const float* g1  = (const float*)d_in[4];
  const float* be1 = (const float*)d_in[5];
  const float* m1  = (const float*)d_in[6];
  const float* v1  = (const float*)d_in[7];
  const float* w2  = (const float*)d_in[8];
  const float* b2  = (const float*)d_in[9];
  const float* g2  = (const float*)d_in[10];
  const float* be2 = (const float*)d_in[11];
  const float* m2  = (const float*)d_in[12];
  const float* v2  = (const float*)d_in[13];
  float* out = (float*)d_out;

  char* ws = (char*)d_ws;
  unsigned short* w1b = (unsigned short*)(ws);                         // 2 MB
  unsigned short* w2b = (unsigned short*)(ws + (2u << 20));            // 256 KB
  float* sc1 = (float*)(ws + (2u << 20) + (256u << 10));
  float* sh1 = sc1 + 512;
  float* sc2 = sh1 + 512;
  float* sh2 = sc2 + 256;
  unsigned short* zt = (unsigned short*)(ws + (4u  << 20));            // 16.8 MB
  unsigned short* h1 = (unsigned short*)(ws + (24u << 20));            // 6.4 MB
  unsigned short* h2 = (unsigned short*)(ws + (32u << 20));            // 3.2 MB
  // total workspace use: ~35.2 MB

  hipLaunchKernelGGL(prep_kernel, dim3(256), dim3(256), 0, stream,
                     w1, w2, b1, g1, be1, m1, v1, b2, g2, be2, m2, v2,
                     w1b, w2b, sc1, sh1, sc2, sh2);
  hipLaunchKernelGGL(conv1_kernel, dim3(256), dim3(512), 0, stream,
                     w1b, feat, zt);
  hipLaunchKernelGGL(roi_gather_kernel, dim3(7, 128), dim3(256), 0, stream,
                     zt, boxes, sc1, sh1, h1);
  hipLaunchKernelGGL(HIP_KERNEL_NAME(gemm_bt_relu<128, 64>),
                     dim3(256 / 64, 6272 / 128), dim3(256), 0, stream,
                     h1, w2b, sc2, sh2, h2, 6272, 256, 512);
  hipLaunchKernelGGL(reduce_kernel, dim3(128), dim3(256), 0, stream, h2, out);
}

// Round 3
// 92.777 us; speedup vs baseline: 2.3077x; 1.1280x over previous
//
#include <hip/hip_runtime.h>

// ---------- helpers ----------
typedef __bf16 bf16x8 __attribute__((ext_vector_type(8)));
typedef float  f32x4  __attribute__((ext_vector_type(4)));
typedef unsigned short u16x8 __attribute__((ext_vector_type(8)));
typedef unsigned int u32;
typedef unsigned long long u64;

static __device__ __forceinline__ unsigned short f32_to_bf16(float f){
  unsigned u = __float_as_uint(f);
  u += 0x7fffu + ((u >> 16) & 1u);          // round-to-nearest-even
  return (unsigned short)(u >> 16);
}
static __device__ __forceinline__ float bf16_to_f32(unsigned short h){
  return __uint_as_float(((unsigned)h) << 16);
}

#define GLOAD_LDS16(g, l)                                                        \
  __builtin_amdgcn_global_load_lds((const __attribute__((address_space(1))) void*)(g), \
                                   (__attribute__((address_space(3))) void*)(l), 16, 0, 0)

// ---------- K0: weight conversion + BN folding ----------
__global__ __launch_bounds__(256) void prep_kernel(
    const float* __restrict__ w1, const float* __restrict__ w2,
    const float* __restrict__ b1, const float* __restrict__ g1, const float* __restrict__ be1,
    const float* __restrict__ m1, const float* __restrict__ v1,
    const float* __restrict__ b2, const float* __restrict__ g2, const float* __restrict__ be2,
    const float* __restrict__ m2, const float* __restrict__ v2,
    unsigned short* __restrict__ w1b, unsigned short* __restrict__ w2b,
    float* __restrict__ sc1, float* __restrict__ sh1,
    float* __restrict__ sc2, float* __restrict__ sh2)
{
  int i = blockIdx.x * 256 + threadIdx.x;
  int stride = gridDim.x * 256;
  for (int k = i; k < 512 * 2048; k += stride) w1b[k] = f32_to_bf16(w1[k]);
  for (int k = i; k < 256 * 512;  k += stride) w2b[k] = f32_to_bf16(w2[k]);
  if (i < 512){
    float s = g1[i] * rsqrtf(v1[i] + 1e-5f);
    sc1[i] = s;
    sh1[i] = (b1[i] - m1[i]) * s + be1[i];   // conv bias folded into BN shift
  } else if (i - 512 < 256){
    int o = i - 512;
    float s = g2[o] * rsqrtf(v2[o] + 1e-5f);
    sc2[o] = s;
    sh2[o] = (b2[o] - m2[o]) * s + be2[o];
  }
}

// ---------- K1: conv1 over full map: Zt[b*4096+p][512] = (W1 . F)^T, bf16 ----------
// grid 512 = 4 b * 64 p-blocks * 2 o-halves; block 256 thr = 4 waves; 2 blocks/CU.
// Double-buffered LDS, counted-vmcnt 2-phase pipeline (no vmcnt(0) drain in loop).
__global__ __launch_bounds__(256, 2) void conv1_kernel(
    const unsigned short* __restrict__ w1b,   // [512][2048] bf16
    const float* __restrict__ feat,           // [4][2048][4096] f32
    unsigned short* __restrict__ zt)          // [4*4096][512] bf16
{
  __shared__ unsigned short ldsA[2][256 * 64];   // 2 x 32KB, swizzled [o][c]
  __shared__ unsigned short ldsB[2][64 * 64];    // 2 x 8KB,  swizzled [p][c]
  int t = threadIdx.x;
  int l = t & 63, wid = t >> 6;

  int bid = blockIdx.x;
  int lid = (bid & 7) * 64 + (bid >> 3);   // XCD-contiguous logical id
  int ohalf = lid & 1;                     // o-half pairs co-resident on one XCD
  int pbid = lid >> 1;                     // 0..255
  int bb = pbid >> 6;
  int p0 = (pbid & 63) << 6;

  // A staging: slot = i*256+t ; row o = 32i + (t>>3); (32i ≡ 0 mod 8 -> swizzle uniform in i)
  int oA = t >> 3;
  int cA = ((((t & 7) << 4) ^ ((oA & 7) << 4)) >> 1);
  const unsigned short* aBase = w1b + ((size_t)(ohalf * 256 + oA)) * 2048 + cA;

  // B staging: thread loads rows c0..c0+3 (f32x4 along p at p4), coalesced
  int c0 = (t >> 4) << 2;
  int p4 = (t & 15) << 2;
  const float* fBase = feat + ((size_t)(bb * 2048 + c0)) * 4096 + p0 + p4;

  f32x4 acc[4][4];
  f32x4 z4 = {0.f, 0.f, 0.f, 0.f};
  #pragma unroll
  for (int m = 0; m < 4; ++m)
    #pragma unroll
    for (int n = 0; n < 4; ++n) acc[m][n] = z4;

  f32x4 rb0[4], rb1[4];

#define STAGE_A(buf, kt) do {                                              \
    _Pragma("unroll")                                                      \
    for (int i = 0; i < 8; ++i)                                            \
      GLOAD_LDS16(aBase + (kt) + (size_t)i * (32 * 2048),                  \
                  (unsigned short*)ldsA[buf] + ((i * 256 + t) * 8));       \
  } while (0)

#define LOAD_B(dst, kt) do {                                               \
    const float* fp_ = fBase + (size_t)(kt) * 4096;                        \
    dst[0] = *(const f32x4*)(fp_);                                         \
    dst[1] = *(const f32x4*)(fp_ + 4096);                                  \
    dst[2] = *(const f32x4*)(fp_ + 8192);                                  \
    dst[3] = *(const f32x4*)(fp_ + 12288);                                 \
  } while (0)

#define WRITE_B(buf, src) do {                                             \
    _Pragma("unroll")                                                      \
    for (int j = 0; j < 4; ++j){                                           \
      int p_ = p4 + j;                                                     \
      u32 lo_ = ((u32)f32_to_bf16(src[0][j])) | (((u32)f32_to_bf16(src[1][j])) << 16); \
      u32 hi_ = ((u32)f32_to_bf16(src[2][j])) | (((u32)f32_to_bf16(src[3][j])) << 16); \
      u64 v_ = ((u64)hi_ << 32) | lo_;                                     \
      *(u64*)((char*)ldsB[buf] + p_ * 128 + ((c0 * 2) ^ ((p_ & 7) << 4))) = v_; \
    }                                                                      \
  } while (0)

#define MFMA_STEP(buf) do {                                                \
    __builtin_amdgcn_s_setprio(1);                                         \
    _Pragma("unroll")                                                      \
    for (int ks = 0; ks < 2; ++ks){                                        \
      bf16x8 af_[4], bf_[4];                                               \
      int cbyte_ = ks * 64 + (l >> 4) * 16;                                \
      _Pragma("unroll")                                                    \
      for (int m = 0; m < 4; ++m){                                         \
        int o_ = wid * 64 + m * 16 + (l & 15);                             \
        af_[m] = *(const bf16x8*)((const char*)ldsA[buf] + o_ * 128 + (cbyte_ ^ ((o_ & 7) << 4))); \
      }                                                                    \
      _Pragma("unroll")                                                    \
      for (int n = 0; n < 4; ++n){                                         \
        int p_ = n * 16 + (l & 15);                                        \
        bf_[n] = *(const bf16x8*)((const char*)ldsB[buf] + p_ * 128 + (cbyte_ ^ ((p_ & 7) << 4))); \
      }                                                                    \
      _Pragma("unroll")                                                    \
      for (int m = 0; m < 4; ++m)                                          \
        _Pragma("unroll")                                                  \
        for (int n = 0; n < 4; ++n)                                        \
          acc[m][n] = __builtin_amdgcn_mfma_f32_16x16x32_bf16(af_[m], bf_[n], acc[m][n], 0, 0, 0); \
    }                                                                      \
    __builtin_amdgcn_s_setprio(0);                                         \
  } while (0)

#define SUBITER(cur, nxt, rcon, rload, ktA, ktB) do {                      \
    STAGE_A(nxt, (ktA));                                                   \
    __builtin_amdgcn_sched_barrier(0);                                     \
    LOAD_B(rload, (ktB));                                                  \
    __builtin_amdgcn_sched_barrier(0);                                     \
    MFMA_STEP(cur);                                                        \
    asm volatile("s_waitcnt vmcnt(4)" ::: "memory");                       \
    __builtin_amdgcn_sched_barrier(0);                                     \
    WRITE_B(nxt, rcon);                                                    \
    asm volatile("s_waitcnt lgkmcnt(0)" ::: "memory");                     \
    __builtin_amdgcn_s_barrier();                                          \
  } while (0)

  // prologue: A(0)->bufA0, B(0)->rb0, B(64)->rb1 ; publish buf0
  STAGE_A(0, 0);
  __builtin_amdgcn_sched_barrier(0);
  LOAD_B(rb0, 0);
  __builtin_amdgcn_sched_barrier(0);
  LOAD_B(rb1, 64);
  __builtin_amdgcn_sched_barrier(0);
  asm volatile("s_waitcnt vmcnt(4)" ::: "memory");   // A(0)+rb0 landed; rb1 in flight
  WRITE_B(0, rb0);
  asm volatile("s_waitcnt lgkmcnt(0)" ::: "memory");
  __builtin_amdgcn_s_barrier();

  for (int t2 = 0; t2 < 16; ++t2){
    int ktc = t2 << 7;                                   // kt of even sub-iter
    int kA0 = min(ktc + 64, 1984), kB0 = min(ktc + 128, 1984);
    SUBITER(0, 1, rb1, rb0, kA0, kB0);                   // compute kt=ktc
    int kA1 = min(ktc + 128, 1984), kB1 = min(ktc + 192, 1984);
    SUBITER(1, 0, rb0, rb1, kA1, kB1);                   // compute kt=ktc+64
  }
  __syncthreads();   // drain leftovers; ldsA[0] reused below

  // epilogue: stage 256o x 64p tile transposed into ldsA[0] as [64p][256o*2B]
  #pragma unroll
  for (int m = 0; m < 4; ++m){
    int o0 = wid * 64 + m * 16 + (l >> 4) * 4;
    #pragma unroll
    for (int n = 0; n < 4; ++n){
      int p = n * 16 + (l & 15);
      u32 lo = ((u32)f32_to_bf16(acc[m][n][0])) | (((u32)f32_to_bf16(acc[m][n][1])) << 16);
      u32 hi = ((u32)f32_to_bf16(acc[m][n][2])) | (((u32)f32_to_bf16(acc[m][n][3])) << 16);
      u64 v = ((u64)hi << 32) | lo;
      *(u64*)((char*)ldsA[0] + p * 512 + ((o0 * 2) ^ ((p & 7) << 4))) = v;
    }
  }
  __syncthreads();
  {
    int p = t >> 2, a = t & 3;
    size_t rowb = ((size_t)(bb * 4096 + p0 + p)) * 1024 + (size_t)ohalf * 512;
    int swz = (p & 7) << 4;
    #pragma unroll
    for (int j = 0; j < 8; ++j){
      int y = (a * 128 + j * 16) ^ swz;
      f32x4 v = *(const f32x4*)((char*)ldsA[0] + p * 512 + y);
      *(f32x4*)((char*)zt + rowb + a * 128 + j * 16) = v;
    }
  }
#undef STAGE_A
#undef LOAD_B
#undef WRITE_B
#undef MFMA_STEP
#undef SUBITER
}

// ---------- K2: ROI gather on Zt (512 ch) + BN1 + ReLU -> h1 bf16 [6272][512] ----------
__global__ __launch_bounds__(256) void roi_gather_kernel(
    const unsigned short* __restrict__ zt, const float* __restrict__ boxes,
    const float* __restrict__ sc1, const float* __restrict__ sh1,
    unsigned short* __restrict__ h1)
{
  int ky = blockIdx.x, roi = blockIdx.y;
  __shared__ int   sIdx[16][8];
  __shared__ float sW[16][8];
  int t = threadIdx.x;

  int   b   = (int)boxes[roi * 5 + 0];
  float bx1 = boxes[roi * 5 + 1], by1 = boxes[roi * 5 + 2];
  float bx2 = boxes[roi * 5 + 3], by2 = boxes[roi * 5 + 4];
  float rw = fmaxf(bx2 - bx1, 1.f), rh = fmaxf(by2 - by1, 1.f);
  float bw = rw * (1.f / 7.f), bh = rh * (1.f / 7.f);

  if (t < 28){
    int kx = t >> 2, s = t & 3;
    int sy = s >> 1, sx = s & 1;
    float yy = by1 + ((float)ky + ((float)sy + 0.5f) * 0.5f) * bh;
    float xx = bx1 + ((float)kx + ((float)sx + 0.5f) * 0.5f) * bw;
    bool vy = (yy >= -1.f) && (yy <= 64.f);
    bool vx = (xx >= -1.f) && (xx <= 64.f);
    float yc = fminf(fmaxf(yy, 0.f), 63.f);
    float xc = fminf(fmaxf(xx, 0.f), 63.f);
    int iy0 = (int)yc, ix0 = (int)xc;
    int iy1 = min(iy0 + 1, 63), ix1 = min(ix0 + 1, 63);
    float fy = yc - (float)iy0, fx = xc - (float)ix0;
    float v = (vy && vx) ? 0.25f : 0.f;
    float wy0 = 1.f - fy, wx0 = 1.f - fx;
    sIdx[s * 4 + 0][kx] = iy0 * 64 + ix0;  sW[s * 4 + 0][kx] = wy0 * wx0 * v;
    sIdx[s * 4 + 1][kx] = iy0 * 64 + ix1;  sW[s * 4 + 1][kx] = wy0 * fx  * v;
    sIdx[s * 4 + 2][kx] = iy1 * 64 + ix0;  sW[s * 4 + 2][kx] = fy  * wx0 * v;
    sIdx[s * 4 + 3][kx] = iy1 * 64 + ix1;  sW[s * 4 + 3][kx] = fy  * fx  * v;
  }
  __syncthreads();

  int w = t >> 6, l = t & 63;
  f32x4 s0 = *(const f32x4*)(sc1 + l * 8);
  f32x4 s1 = *(const f32x4*)(sc1 + l * 8 + 4);
  f32x4 h0 = *(const f32x4*)(sh1 + l * 8);
  f32x4 hh = *(const f32x4*)(sh1 + l * 8 + 4);
  const unsigned short* zb = zt + ((size_t)b * 4096) * 512 + l * 8;

  for (int kx = w; kx < 7; kx += 4){
    float a[8];
    #pragma unroll
    for (int j = 0; j < 8; ++j) a[j] = 0.f;
    #pragma unroll
    for (int i = 0; i < 16; ++i){
      int idx = sIdx[i][kx];
      float wt = sW[i][kx];
      u16x8 v = *(const u16x8*)(zb + (size_t)idx * 512);
      #pragma unroll
      for (int j = 0; j < 8; ++j) a[j] += wt * bf16_to_f32(v[j]);
    }
    u16x8 o;
    #pragma unroll
    for (int j = 0; j < 4; ++j){
      float v0 = fmaxf(a[j] * s0[j] + h0[j], 0.f);
      float v1 = fmaxf(a[j + 4] * s1[j] + hh[j], 0.f);
      o[j] = f32_to_bf16(v0);
      o[j + 4] = f32_to_bf16(v1);
    }
    *(u16x8*)(h1 + ((size_t)(roi * 49 + ky * 7 + kx)) * 512 + l * 8) = o;
  }
}

// ---------- K3: bf16 GEMM, B-transposed input, fused scale/shift + ReLU ----------
template<int BM, int BN>
__global__ __launch_bounds__(256) void gemm_bt_relu(
    const unsigned short* __restrict__ A, const unsigned short* __restrict__ Bt,
    const float* __restrict__ scale, const float* __restrict__ shift,
    unsigned short* __restrict__ C, int M, int N, int K)
{
  constexpr int BK = 64;
  constexpr int FM = BM / 32;
  constexpr int FN = BN / 32;
  __shared__ unsigned short lds_a[BM * BK];
  __shared__ unsigned short lds_b[BN * BK];
  int t = threadIdx.x;
  int l = t & 63, wid = t >> 6;
  int wr = wid >> 1, wc = wid & 1;
  int m0 = blockIdx.y * BM, n0 = blockIdx.x * BN;

  f32x4 acc[FM][FN];
  f32x4 z = {0.f, 0.f, 0.f, 0.f};
  #pragma unroll
  for (int m = 0; m < FM; ++m)
    #pragma unroll
    for (int n = 0; n < FN; ++n) acc[m][n] = z;

  const unsigned short* Ab = A  + (size_t)m0 * K;
  const unsigned short* Bb = Bt + (size_t)n0 * K;

  for (int kt = 0; kt < K; kt += BK){
    #pragma unroll
    for (int r = 0; r < BM / 32; ++r){
      int row = r * 32 + (t >> 3);
      GLOAD_LDS16(Ab + (size_t)row * K + kt + (t & 7) * 8,
                  lds_a + row * BK + (t & 7) * 8);
    }
    #pragma unroll
    for (int r = 0; r < BN / 32; ++r){
      int row = r * 32 + (t >> 3);
      GLOAD_LDS16(Bb + (size_t)row * K + kt + (t & 7) * 8,
                  lds_b + row * BK + (t & 7) * 8);
    }
    __syncthreads();
    #pragma unroll
    for (int ks = 0; ks < 2; ++ks){
      bf16x8 af[FM], bfr[FN];
      #pragma unroll
      for (int m = 0; m < FM; ++m)
        af[m] = *reinterpret_cast<const bf16x8*>(
            lds_a + (wr * (BM / 2) + m * 16 + (l & 15)) * BK + ks * 32 + (l >> 4) * 8);
      #pragma unroll
      for (int n = 0; n < FN; ++n)
        bfr[n] = *reinterpret_cast<const bf16x8*>(
            lds_b + (wc * (BN / 2) + n * 16 + (l & 15)) * BK + ks * 32 + (l >> 4) * 8);
      #pragma unroll
      for (int m = 0; m < FM; ++m)
        #pragma unroll
        for (int n = 0; n < FN; ++n)
          acc[m][n] = __builtin_amdgcn_mfma_f32_16x16x32_bf16(af[m], bfr[n], acc[m][n], 0, 0, 0);
    }
    __syncthreads();
  }

  #pragma unroll
  for (int m = 0; m < FM; ++m){
    int gr = m0 + wr * (BM / 2) + m * 16 + (l >> 4) * 4;
    #pragma unroll
    for (int n = 0; n < FN; ++n){
      int gc = n0 + wc * (BN / 2) + n * 16 + (l & 15);
      float sc = scale[gc], sh = shift[gc];
      #pragma unroll
      for (int r = 0; r < 4; ++r){
        float v = acc[m][n][r] * sc + sh;
        v = fmaxf(v, 0.f);
        C[(size_t)(gr + r) * N + gc] = f32_to_bf16(v);
      }
    }
  }
}

// ---------- K4: mean over 49 bins -> out f32 [128][256] ----------
__global__ __launch_bounds__(256) void reduce_kernel(
    const unsigned short* __restrict__ h2, float* __restrict__ out)
{
  int n = blockIdx.x, o = threadIdx.x;
  const unsigned short* p = h2 + (size_t)n * 49 * 256 + o;
  float s = 0.f;
  for (int j = 0; j < 49; ++j) s += bf16_to_f32(p[j * 256]);
  out[n * 256 + o] = s * (1.f / 49.f);
}

// ---------- launch ----------
extern "C" void kernel_launch(void* const* d_in, const int* in_sizes, int n_in,
                              void* d_out, int out_size, void* d_ws, size_t ws_size,
                              hipStream_t stream)
{
  const float* feat  = (const float*)d_in[0];
  const float* boxes = (const float*)d_in[1];
  const float* w1  = (const float*)d_in[2];
  const float* b1  = (const float*)d_in[3];
  const float* g1  = (const float*)d_in[4];
  const float* be1 = (const float*)d_in[5];
  const float* m1  = (const float*)d_in[6];
  const float* v1  = (const float*)d_in[7];
  const float* w2  = (const float*)d_in[8];
  const float* b2  = (const float*)d_in[9];
  const float* g2  = (const float*)d_in[10];
  const float* be2 = (const float*)d_in[11];
  const float* m2  = (const float*)d_in[12];
  const float* v2  = (const float*)d_in[13];
  float* out = (float*)d_out;

  char* ws = (char*)d_ws;
  unsigned short* w1b = (unsigned short*)(ws);                         // 2 MB
  unsigned short* w2b = (unsigned short*)(ws + (2u << 20));            // 256 KB
  float* sc1 = (float*)(ws + (2u << 20) + (256u << 10));
  float* sh1 = sc1 + 512;
  float* sc2 = sh1 + 512;
  float* sh2 = sc2 + 256;
  unsigned short* zt = (unsigned short*)(ws + (4u  << 20));            // 16.8 MB
  unsigned short* h1 = (unsigned short*)(ws + (24u << 20));            // 6.4 MB
  unsigned short* h2 = (unsigned short*)(ws + (32u << 20));            // 3.2 MB

  hipLaunchKernelGGL(prep_kernel, dim3(256), dim3(256), 0, stream,
                     w1, w2, b1, g1, be1, m1, v1, b2, g2, be2, m2, v2,
                     w1b, w2b, sc1, sh1, sc2, sh2);
  hipLaunchKernelGGL(conv1_kernel, dim3(512), dim3(256), 0, stream,
                     w1b, feat, zt);
  hipLaunchKernelGGL(roi_gather_kernel, dim3(7, 128), dim3(256), 0, stream,
                     zt, boxes, sc1, sh1, h1);
  hipLaunchKernelGGL(HIP_KERNEL_NAME(gemm_bt_relu<128, 64>),
                     dim3(256 / 64, 6272 / 128), dim3(256), 0, stream,
                     h1, w2b, sc2, sh2, h2, 6272, 256, 512);
  hipLaunchKernelGGL(reduce_kernel, dim3(128), dim3(256), 0, stream, h2, out);
}

// Round 4
// 90.635 us; speedup vs baseline: 2.3623x; 1.0236x over previous
//
#include <hip/hip_runtime.h>

// ---------- helpers ----------
typedef __bf16 bf16x8 __attribute__((ext_vector_type(8)));
typedef float  f32x4  __attribute__((ext_vector_type(4)));
typedef unsigned short u16x8 __attribute__((ext_vector_type(8)));
typedef unsigned int u32;
typedef unsigned long long u64;

static __device__ __forceinline__ unsigned short f32_to_bf16(float f){
  unsigned u = __float_as_uint(f);
  u += 0x7fffu + ((u >> 16) & 1u);          // round-to-nearest-even
  return (unsigned short)(u >> 16);
}
static __device__ __forceinline__ float bf16_to_f32(unsigned short h){
  return __uint_as_float(((unsigned)h) << 16);
}

#define GLOAD_LDS16(g, l)                                                        \
  __builtin_amdgcn_global_load_lds((const __attribute__((address_space(1))) void*)(g), \
                                   (__attribute__((address_space(3))) void*)(l), 16, 0, 0)

// ---------- K0: weight conversion + BN folding ----------
__global__ __launch_bounds__(256) void prep_kernel(
    const float* __restrict__ w1, const float* __restrict__ w2,
    const float* __restrict__ b1, const float* __restrict__ g1, const float* __restrict__ be1,
    const float* __restrict__ m1, const float* __restrict__ v1,
    const float* __restrict__ b2, const float* __restrict__ g2, const float* __restrict__ be2,
    const float* __restrict__ m2, const float* __restrict__ v2,
    unsigned short* __restrict__ w1b, unsigned short* __restrict__ w2b,
    float* __restrict__ sc1, float* __restrict__ sh1,
    float* __restrict__ sc2, float* __restrict__ sh2)
{
  int i = blockIdx.x * 256 + threadIdx.x;
  int stride = gridDim.x * 256;
  for (int k = i; k < 512 * 2048; k += stride) w1b[k] = f32_to_bf16(w1[k]);
  for (int k = i; k < 256 * 512;  k += stride) w2b[k] = f32_to_bf16(w2[k]);
  if (i < 512){
    float s = g1[i] * rsqrtf(v1[i] + 1e-5f);
    sc1[i] = s;
    sh1[i] = (b1[i] - m1[i]) * s + be1[i];   // conv bias folded into BN shift
  } else if (i - 512 < 256){
    int o = i - 512;
    float s = g2[o] * rsqrtf(v2[o] + 1e-5f);
    sc2[o] = s;
    sh2[o] = (b2[o] - m2[o]) * s + be2[o];
  }
}

// ---------- K1: conv1 over full map: Zt[b*4096+p][512] = (W1 . F)^T, bf16 ----------
// grid 512 = 4 b * 64 p-blocks * 2 o-halves; block 256 thr = 4 waves; 2 blocks/CU.
// Double-buffered LDS, counted-vmcnt 2-phase pipeline (no vmcnt(0) drain in loop).
// B-row swizzle key f(p) = (p ^ (p>>3)) & 7: 2-way (free) on BOTH ds_write_b64
// staging (p = 4*lane+j per quarter) and ds_read_b128 frags (p = 16n + lane).
__global__ __launch_bounds__(256, 2) void conv1_kernel(
    const unsigned short* __restrict__ w1b,   // [512][2048] bf16
    const float* __restrict__ feat,           // [4][2048][4096] f32
    unsigned short* __restrict__ zt)          // [4*4096][512] bf16
{
  __shared__ unsigned short ldsA[2][256 * 64];   // 2 x 32KB, swizzled [o][c]
  __shared__ unsigned short ldsB[2][64 * 64];    // 2 x 8KB,  swizzled [p][c]
  int t = threadIdx.x;
  int l = t & 63, wid = t >> 6;

  int bid = blockIdx.x;
  int lid = (bid & 7) * 64 + (bid >> 3);   // XCD-contiguous logical id
  int ohalf = lid & 1;                     // o-half pairs co-resident on one XCD
  int pbid = lid >> 1;                     // 0..255
  int bb = pbid >> 6;
  int p0 = (pbid & 63) << 6;

  // A staging: slot = i*256+t ; row o = 32i + (t>>3); (32i ≡ 0 mod 8 -> swizzle uniform in i)
  int oA = t >> 3;
  int cA = ((((t & 7) << 4) ^ ((oA & 7) << 4)) >> 1);
  const unsigned short* aBase = w1b + ((size_t)(ohalf * 256 + oA)) * 2048 + cA;

  // B staging: thread loads rows c0..c0+3 (f32x4 along p at p4), coalesced
  int c0 = (t >> 4) << 2;
  int p4 = (t & 15) << 2;
  const float* fBase = feat + ((size_t)(bb * 2048 + c0)) * 4096 + p0 + p4;

  f32x4 acc[4][4];
  f32x4 z4 = {0.f, 0.f, 0.f, 0.f};
  #pragma unroll
  for (int m = 0; m < 4; ++m)
    #pragma unroll
    for (int n = 0; n < 4; ++n) acc[m][n] = z4;

  f32x4 rb0[4], rb1[4];

#define STAGE_A(buf, kt) do {                                              \
    _Pragma("unroll")                                                      \
    for (int i = 0; i < 8; ++i)                                            \
      GLOAD_LDS16(aBase + (kt) + (size_t)i * (32 * 2048),                  \
                  (unsigned short*)ldsA[buf] + ((i * 256 + t) * 8));       \
  } while (0)

#define LOAD_B(dst, kt) do {                                               \
    const float* fp_ = fBase + (size_t)(kt) * 4096;                        \
    dst[0] = *(const f32x4*)(fp_);                                         \
    dst[1] = *(const f32x4*)(fp_ + 4096);                                  \
    dst[2] = *(const f32x4*)(fp_ + 8192);                                  \
    dst[3] = *(const f32x4*)(fp_ + 12288);                                 \
  } while (0)

#define WRITE_B(buf, src) do {                                             \
    _Pragma("unroll")                                                      \
    for (int j = 0; j < 4; ++j){                                           \
      int p_ = p4 + j;                                                     \
      int f_ = (p_ ^ (p_ >> 3)) & 7;                                       \
      u32 lo_ = ((u32)f32_to_bf16(src[0][j])) | (((u32)f32_to_bf16(src[1][j])) << 16); \
      u32 hi_ = ((u32)f32_to_bf16(src[2][j])) | (((u32)f32_to_bf16(src[3][j])) << 16); \
      u64 v_ = ((u64)hi_ << 32) | lo_;                                     \
      *(u64*)((char*)ldsB[buf] + p_ * 128 + ((c0 * 2) ^ (f_ << 4))) = v_;  \
    }                                                                      \
  } while (0)

#define MFMA_STEP(buf) do {                                                \
    __builtin_amdgcn_s_setprio(1);                                         \
    _Pragma("unroll")                                                      \
    for (int ks = 0; ks < 2; ++ks){                                        \
      bf16x8 af_[4], bf_[4];                                               \
      int cbyte_ = ks * 64 + (l >> 4) * 16;                                \
      _Pragma("unroll")                                                    \
      for (int m = 0; m < 4; ++m){                                         \
        int o_ = wid * 64 + m * 16 + (l & 15);                             \
        af_[m] = *(const bf16x8*)((const char*)ldsA[buf] + o_ * 128 + (cbyte_ ^ ((o_ & 7) << 4))); \
      }                                                                    \
      _Pragma("unroll")                                                    \
      for (int n = 0; n < 4; ++n){                                         \
        int p_ = n * 16 + (l & 15);                                        \
        int f_ = (p_ ^ (p_ >> 3)) & 7;                                     \
        bf_[n] = *(const bf16x8*)((const char*)ldsB[buf] + p_ * 128 + (cbyte_ ^ (f_ << 4))); \
      }                                                                    \
      _Pragma("unroll")                                                    \
      for (int m = 0; m < 4; ++m)                                          \
        _Pragma("unroll")                                                  \
        for (int n = 0; n < 4; ++n)                                        \
          acc[m][n] = __builtin_amdgcn_mfma_f32_16x16x32_bf16(af_[m], bf_[n], acc[m][n], 0, 0, 0); \
    }                                                                      \
    __builtin_amdgcn_s_setprio(0);                                         \
  } while (0)

#define SUBITER(cur, nxt, rcon, rload, ktA, ktB) do {                      \
    STAGE_A(nxt, (ktA));                                                   \
    __builtin_amdgcn_sched_barrier(0);                                     \
    LOAD_B(rload, (ktB));                                                  \
    __builtin_amdgcn_sched_barrier(0);                                     \
    MFMA_STEP(cur);                                                        \
    asm volatile("s_waitcnt vmcnt(4)" ::: "memory");                       \
    __builtin_amdgcn_sched_barrier(0);                                     \
    WRITE_B(nxt, rcon);                                                    \
    asm volatile("s_waitcnt lgkmcnt(0)" ::: "memory");                     \
    __builtin_amdgcn_s_barrier();                                          \
  } while (0)

  // prologue: A(0)->bufA0, B(0)->rb0, B(64)->rb1 ; publish buf0
  STAGE_A(0, 0);
  __builtin_amdgcn_sched_barrier(0);
  LOAD_B(rb0, 0);
  __builtin_amdgcn_sched_barrier(0);
  LOAD_B(rb1, 64);
  __builtin_amdgcn_sched_barrier(0);
  asm volatile("s_waitcnt vmcnt(4)" ::: "memory");   // A(0)+rb0 landed; rb1 in flight
  WRITE_B(0, rb0);
  asm volatile("s_waitcnt lgkmcnt(0)" ::: "memory");
  __builtin_amdgcn_s_barrier();

  for (int t2 = 0; t2 < 16; ++t2){
    int ktc = t2 << 7;                                   // kt of even sub-iter
    int kA0 = min(ktc + 64, 1984), kB0 = min(ktc + 128, 1984);
    SUBITER(0, 1, rb1, rb0, kA0, kB0);                   // compute kt=ktc
    int kA1 = min(ktc + 128, 1984), kB1 = min(ktc + 192, 1984);
    SUBITER(1, 0, rb0, rb1, kA1, kB1);                   // compute kt=ktc+64
  }
  __syncthreads();   // drain leftovers; ldsA[0] reused below

  // epilogue: stage 256o x 64p tile transposed into ldsA[0] as [64p][256o*2B]
  #pragma unroll
  for (int m = 0; m < 4; ++m){
    int o0 = wid * 64 + m * 16 + (l >> 4) * 4;
    #pragma unroll
    for (int n = 0; n < 4; ++n){
      int p = n * 16 + (l & 15);
      u32 lo = ((u32)f32_to_bf16(acc[m][n][0])) | (((u32)f32_to_bf16(acc[m][n][1])) << 16);
      u32 hi = ((u32)f32_to_bf16(acc[m][n][2])) | (((u32)f32_to_bf16(acc[m][n][3])) << 16);
      u64 v = ((u64)hi << 32) | lo;
      *(u64*)((char*)ldsA[0] + p * 512 + ((o0 * 2) ^ ((p & 7) << 4))) = v;
    }
  }
  __syncthreads();
  {
    int p = t >> 2, a = t & 3;
    size_t rowb = ((size_t)(bb * 4096 + p0 + p)) * 1024 + (size_t)ohalf * 512;
    int swz = (p & 7) << 4;
    #pragma unroll
    for (int j = 0; j < 8; ++j){
      int y = (a * 128 + j * 16) ^ swz;
      f32x4 v = *(const f32x4*)((char*)ldsA[0] + p * 512 + y);
      *(f32x4*)((char*)zt + rowb + a * 128 + j * 16) = v;
    }
  }
#undef STAGE_A
#undef LOAD_B
#undef WRITE_B
#undef MFMA_STEP
#undef SUBITER
}

// ---------- K2: ROI gather on Zt (512 ch) + BN1 + ReLU -> h1 bf16 [6272][512] ----------
__global__ __launch_bounds__(256) void roi_gather_kernel(
    const unsigned short* __restrict__ zt, const float* __restrict__ boxes,
    const float* __restrict__ sc1, const float* __restrict__ sh1,
    unsigned short* __restrict__ h1)
{
  int ky = blockIdx.x, roi = blockIdx.y;
  __shared__ int   sIdx[16][8];
  __shared__ float sW[16][8];
  int t = threadIdx.x;

  int   b   = (int)boxes[roi * 5 + 0];
  float bx1 = boxes[roi * 5 + 1], by1 = boxes[roi * 5 + 2];
  float bx2 = boxes[roi * 5 + 3], by2 = boxes[roi * 5 + 4];
  float rw = fmaxf(bx2 - bx1, 1.f), rh = fmaxf(by2 - by1, 1.f);
  float bw = rw * (1.f / 7.f), bh = rh * (1.f / 7.f);

  if (t < 28){
    int kx = t >> 2, s = t & 3;
    int sy = s >> 1, sx = s & 1;
    float yy = by1 + ((float)ky + ((float)sy + 0.5f) * 0.5f) * bh;
    float xx = bx1 + ((float)kx + ((float)sx + 0.5f) * 0.5f) * bw;
    bool vy = (yy >= -1.f) && (yy <= 64.f);
    bool vx = (xx >= -1.f) && (xx <= 64.f);
    float yc = fminf(fmaxf(yy, 0.f), 63.f);
    float xc = fminf(fmaxf(xx, 0.f), 63.f);
    int iy0 = (int)yc, ix0 = (int)xc;
    int iy1 = min(iy0 + 1, 63), ix1 = min(ix0 + 1, 63);
    float fy = yc - (float)iy0, fx = xc - (float)ix0;
    float v = (vy && vx) ? 0.25f : 0.f;
    float wy0 = 1.f - fy, wx0 = 1.f - fx;
    sIdx[s * 4 + 0][kx] = iy0 * 64 + ix0;  sW[s * 4 + 0][kx] = wy0 * wx0 * v;
    sIdx[s * 4 + 1][kx] = iy0 * 64 + ix1;  sW[s * 4 + 1][kx] = wy0 * fx  * v;
    sIdx[s * 4 + 2][kx] = iy1 * 64 + ix0;  sW[s * 4 + 2][kx] = fy  * wx0 * v;
    sIdx[s * 4 + 3][kx] = iy1 * 64 + ix1;  sW[s * 4 + 3][kx] = fy  * fx  * v;
  }
  __syncthreads();

  int w = t >> 6, l = t & 63;
  f32x4 s0 = *(const f32x4*)(sc1 + l * 8);
  f32x4 s1 = *(const f32x4*)(sc1 + l * 8 + 4);
  f32x4 h0 = *(const f32x4*)(sh1 + l * 8);
  f32x4 hh = *(const f32x4*)(sh1 + l * 8 + 4);
  const unsigned short* zb = zt + ((size_t)b * 4096) * 512 + l * 8;

  for (int kx = w; kx < 7; kx += 4){
    float a[8];
    #pragma unroll
    for (int j = 0; j < 8; ++j) a[j] = 0.f;
    #pragma unroll
    for (int i = 0; i < 16; ++i){
      int idx = sIdx[i][kx];
      float wt = sW[i][kx];
      u16x8 v = *(const u16x8*)(zb + (size_t)idx * 512);
      #pragma unroll
      for (int j = 0; j < 8; ++j) a[j] += wt * bf16_to_f32(v[j]);
    }
    u16x8 o;
    #pragma unroll
    for (int j = 0; j < 4; ++j){
      float v0 = fmaxf(a[j] * s0[j] + h0[j], 0.f);
      float v1 = fmaxf(a[j + 4] * s1[j] + hh[j], 0.f);
      o[j] = f32_to_bf16(v0);
      o[j + 4] = f32_to_bf16(v1);
    }
    *(u16x8*)(h1 + ((size_t)(roi * 49 + ky * 7 + kx)) * 512 + l * 8) = o;
  }
}

// ---------- K3: bf16 GEMM, B-transposed input, fused scale/shift + ReLU ----------
template<int BM, int BN>
__global__ __launch_bounds__(256) void gemm_bt_relu(
    const unsigned short* __restrict__ A, const unsigned short* __restrict__ Bt,
    const float* __restrict__ scale, const float* __restrict__ shift,
    unsigned short* __restrict__ C, int M, int N, int K)
{
  constexpr int BK = 64;
  constexpr int FM = BM / 32;
  constexpr int FN = BN / 32;
  __shared__ unsigned short lds_a[BM * BK];
  __shared__ unsigned short lds_b[BN * BK];
  int t = threadIdx.x;
  int l = t & 63, wid = t >> 6;
  int wr = wid >> 1, wc = wid & 1;
  int m0 = blockIdx.y * BM, n0 = blockIdx.x * BN;

  f32x4 acc[FM][FN];
  f32x4 z = {0.f, 0.f, 0.f, 0.f};
  #pragma unroll
  for (int m = 0; m < FM; ++m)
    #pragma unroll
    for (int n = 0; n < FN; ++n) acc[m][n] = z;

  const unsigned short* Ab = A  + (size_t)m0 * K;
  const unsigned short* Bb = Bt + (size_t)n0 * K;

  for (int kt = 0; kt < K; kt += BK){
    #pragma unroll
    for (int r = 0; r < BM / 32; ++r){
      int row = r * 32 + (t >> 3);
      GLOAD_LDS16(Ab + (size_t)row * K + kt + (t & 7) * 8,
                  lds_a + row * BK + (t & 7) * 8);
    }
    #pragma unroll
    for (int r = 0; r < BN / 32; ++r){
      int row = r * 32 + (t >> 3);
      GLOAD_LDS16(Bb + (size_t)row * K + kt + (t & 7) * 8,
                  lds_b + row * BK + (t & 7) * 8);
    }
    __syncthreads();
    #pragma unroll
    for (int ks = 0; ks < 2; ++ks){
      bf16x8 af[FM], bfr[FN];
      #pragma unroll
      for (int m = 0; m < FM; ++m)
        af[m] = *reinterpret_cast<const bf16x8*>(
            lds_a + (wr * (BM / 2) + m * 16 + (l & 15)) * BK + ks * 32 + (l >> 4) * 8);
      #pragma unroll
      for (int n = 0; n < FN; ++n)
        bfr[n] = *reinterpret_cast<const bf16x8*>(
            lds_b + (wc * (BN / 2) + n * 16 + (l & 15)) * BK + ks * 32 + (l >> 4) * 8);
      #pragma unroll
      for (int m = 0; m < FM; ++m)
        #pragma unroll
        for (int n = 0; n < FN; ++n)
          acc[m][n] = __builtin_amdgcn_mfma_f32_16x16x32_bf16(af[m], bfr[n], acc[m][n], 0, 0, 0);
    }
    __syncthreads();
  }

  #pragma unroll
  for (int m = 0; m < FM; ++m){
    int gr = m0 + wr * (BM / 2) + m * 16 + (l >> 4) * 4;
    #pragma unroll
    for (int n = 0; n < FN; ++n){
      int gc = n0 + wc * (BN / 2) + n * 16 + (l & 15);
      float sc = scale[gc], sh = shift[gc];
      #pragma unroll
      for (int r = 0; r < 4; ++r){
        float v = acc[m][n][r] * sc + sh;
        v = fmaxf(v, 0.f);
        C[(size_t)(gr + r) * N + gc] = f32_to_bf16(v);
      }
    }
  }
}

// ---------- K4: mean over 49 bins -> out f32 [128][256] ----------
__global__ __launch_bounds__(256) void reduce_kernel(
    const unsigned short* __restrict__ h2, float* __restrict__ out)
{
  int n = blockIdx.x, o = threadIdx.x;
  const unsigned short* p = h2 + (size_t)n * 49 * 256 + o;
  float s = 0.f;
  for (int j = 0; j < 49; ++j) s += bf16_to_f32(p[j * 256]);
  out[n * 256 + o] = s * (1.f / 49.f);
}

// ---------- launch ----------
extern "C" void kernel_launch(void* const* d_in, const int* in_sizes, int n_in,
                              void* d_out, int out_size, void* d_ws, size_t ws_size,
                              hipStream_t stream)
{
  const float* feat  = (const float*)d_in[0];
  const float* boxes = (const float*)d_in[1];
  const float* w1  = (const float*)d_in[2];
  const float* b1  = (const float*)d_in[3];
  const float* g1  = (const float*)d_in[4];
  const float* be1 = (const float*)d_in[5];
  const float* m1  = (const float*)d_in[6];
  const float* v1  = (const float*)d_in[7];
  const float* w2  = (const float*)d_in[8];
  const float* b2  = (const float*)d_in[9];
  const float* g2  = (const float*)d_in[10];
  const float* be2 = (const float*)d_in[11];
  const float* m2  = (const float*)d_in[12];
  const float* v2  = (const float*)d_in[13];
  float* out = (float*)d_out;

  char* ws = (char*)d_ws;
  unsigned short* w1b = (unsigned short*)(ws);                         // 2 MB
  unsigned short* w2b = (unsigned short*)(ws + (2u << 20));            // 256 KB
  float* sc1 = (float*)(ws + (2u << 20) + (256u << 10));
  float* sh1 = sc1 + 512;
  float* sc2 = sh1 + 512;
  float* sh2 = sc2 + 256;
  unsigned short* zt = (unsigned short*)(ws + (4u  << 20));            // 16.8 MB
  unsigned short* h1 = (unsigned short*)(ws + (24u << 20));            // 6.4 MB
  unsigned short* h2 = (unsigned short*)(ws + (32u << 20));            // 3.2 MB

  hipLaunchKernelGGL(prep_kernel, dim3(256), dim3(256), 0, stream,
                     w1, w2, b1, g1, be1, m1, v1, b2, g2, be2, m2, v2,
                     w1b, w2b, sc1, sh1, sc2, sh2);
  hipLaunchKernelGGL(conv1_kernel, dim3(512), dim3(256), 0, stream,
                     w1b, feat, zt);
  hipLaunchKernelGGL(roi_gather_kernel, dim3(7, 128), dim3(256), 0, stream,
                     zt, boxes, sc1, sh1, h1);
  hipLaunchKernelGGL(HIP_KERNEL_NAME(gemm_bt_relu<128, 64>),
                     dim3(256 / 64, 6272 / 128), dim3(256), 0, stream,
                     h1, w2b, sc2, sh2, h2, 6272, 256, 512);
  hipLaunchKernelGGL(reduce_kernel, dim3(128), dim3(256), 0, stream, h2, out);
}